// Round 2
// baseline (106.765 us; speedup 1.0000x reference)
//
#include <hip/hip_runtime.h>

#define B 16
#define F_DIM 256
#define P 8192
#define C 96
#define H 256
#define NSEG (B * C)          // 1536
#define ROWS 6                // rows per MLP block -> 256 blocks
#define NBLK (NSEG / ROWS)    // 256
#define KT 16                 // k-tile for H->H layers
#define NT (H / KT)           // 16
#define WV4 (KT * H / 4 / 256)   // 4 float4 per thread per tile
#define KTL 32                // k-tile for logit layer
#define NTL (H / KTL)         // 8
#define LV4 (KTL * C / 4 / 256)  // 3 float4 per thread per tile

// order-preserving float <-> uint mapping for atomicMax-based float max
__device__ __forceinline__ unsigned f2key(float x) {
    unsigned u = __float_as_uint(x);
    return (u & 0x80000000u) ? ~u : (u | 0x80000000u);
}
__device__ __forceinline__ float key2f(unsigned k) {
    unsigned u = (k & 0x80000000u) ? (k & 0x7FFFFFFFu) : ~k;
    return __uint_as_float(u);
}

__global__ __launch_bounds__(256) void count_kernel(const int* __restrict__ label,
                                                    int* __restrict__ counts) {
    __shared__ int hist[C];
    const int b = blockIdx.x;
    const int t = threadIdx.x;
    if (t < C) hist[t] = 0;
    __syncthreads();
    const int* lrow = label + b * P;
    for (int p = t; p < P; p += 256) {
        atomicAdd(&hist[lrow[p]], 1);
    }
    __syncthreads();
    if (t < C) counts[b * C + t] = hist[t];
}

// one block per (b, f): stream 8192 floats + labels, LDS atomicMax per class
__global__ __launch_bounds__(256) void pool_kernel(const float* __restrict__ feat,
                                                   const int* __restrict__ label,
                                                   const int* __restrict__ counts,
                                                   float* __restrict__ pooled) {
    __shared__ unsigned smax[C];
    const int blk = blockIdx.x;
    const int b = blk >> 8;       // / F_DIM
    const int f = blk & 255;      // % F_DIM
    const int t = threadIdx.x;
    if (t < C) smax[t] = 0u;      // key(-inf) > 0, so 0 is a safe identity
    __syncthreads();

    const float4* frow4 = (const float4*)(feat + ((size_t)b * F_DIM + f) * P);
    const int4*   lrow4 = (const int4*)(label + (size_t)b * P);
    for (int i = t; i < P / 4; i += 256) {
        float4 v = frow4[i];
        int4   c = lrow4[i];
        atomicMax(&smax[c.x], f2key(v.x));
        atomicMax(&smax[c.y], f2key(v.y));
        atomicMax(&smax[c.z], f2key(v.z));
        atomicMax(&smax[c.w], f2key(v.w));
    }
    __syncthreads();

    if (t < C) {
        const int cnt = counts[b * C + t];
        const float v = key2f(smax[t]);
        float r = (cnt == 0) ? 0.0f : ((cnt == P) ? v : fmaxf(v, 0.0f));
        pooled[(size_t)(b * C + t) * F_DIM + f] = r;
    }
}

// fused 3-layer MLP, LDS double-buffered weight staging.
// 256 blocks x 256 threads; block owns ROWS=6 consecutive segments.
__global__ __launch_bounds__(256) void mlp_kernel(const float* __restrict__ pooled,
                                                  const float* __restrict__ w1,
                                                  const float* __restrict__ b1,
                                                  const float* __restrict__ w2,
                                                  const float* __restrict__ b2,
                                                  const float* __restrict__ wl,
                                                  const float* __restrict__ bl,
                                                  float* __restrict__ out) {
    __shared__ float wbuf[2][KT * H];   // 2 x 16KB weight tiles
    __shared__ float xs[ROWS][H];
    __shared__ float ys[ROWS][H];
    const int t = threadIdx.x;
    const int row0 = blockIdx.x * ROWS;

    #pragma unroll
    for (int r = 0; r < ROWS; ++r)
        xs[r][t] = pooled[(size_t)(row0 + r) * H + t];
    // visibility covered by first dense()'s prologue barrier

    // ---- dense H->H layer with relu: yout = relu(xin @ w + bias) ----
    auto dense = [&](const float* __restrict__ w, const float* __restrict__ bias,
                     const float (*xin)[H], float (*yout)[H]) {
        const float4* w4 = (const float4*)w;
        float4 pre[WV4];
        #pragma unroll
        for (int i = 0; i < WV4; ++i) pre[i] = w4[i * 256 + t];
        #pragma unroll
        for (int i = 0; i < WV4; ++i) ((float4*)wbuf[0])[i * 256 + t] = pre[i];
        float acc[ROWS];
        const float bv = bias[t];
        #pragma unroll
        for (int r = 0; r < ROWS; ++r) acc[r] = bv;
        __syncthreads();
        int cur = 0;
        for (int kt = 0; kt < NT; ++kt) {
            if (kt + 1 < NT) {
                #pragma unroll
                for (int i = 0; i < WV4; ++i)
                    pre[i] = w4[(size_t)(kt + 1) * (KT * H / 4) + i * 256 + t];
            }
            const float* wb = wbuf[cur];
            #pragma unroll
            for (int k4 = 0; k4 < KT / 4; ++k4) {
                float4 xv[ROWS];
                #pragma unroll
                for (int r = 0; r < ROWS; ++r)
                    xv[r] = ((const float4*)xin[r])[kt * (KT / 4) + k4];
                #pragma unroll
                for (int j = 0; j < 4; ++j) {
                    float wv = wb[(k4 * 4 + j) * H + t];
                    #pragma unroll
                    for (int r = 0; r < ROWS; ++r)
                        acc[r] = fmaf(((const float*)&xv[r])[j], wv, acc[r]);
                }
            }
            if (kt + 1 < NT) {
                #pragma unroll
                for (int i = 0; i < WV4; ++i)
                    ((float4*)wbuf[cur ^ 1])[i * 256 + t] = pre[i];
            }
            __syncthreads();
            cur ^= 1;
        }
        #pragma unroll
        for (int r = 0; r < ROWS; ++r) yout[r][t] = fmaxf(acc[r], 0.0f);
        // visibility covered by next phase's prologue barrier
    };

    dense(w1, b1, xs, ys);
    dense(w2, b2, ys, xs);

    // ---- logits: out_rows = xs @ wl + bl  (H x C, C=96) ----
    {
        const float4* wl4 = (const float4*)wl;
        float4 pre[LV4];
        #pragma unroll
        for (int i = 0; i < LV4; ++i) pre[i] = wl4[i * 256 + t];
        #pragma unroll
        for (int i = 0; i < LV4; ++i) ((float4*)wbuf[0])[i * 256 + t] = pre[i];
        float acc[ROWS];
        const float bv = (t < C) ? bl[t] : 0.0f;
        #pragma unroll
        for (int r = 0; r < ROWS; ++r) acc[r] = bv;
        __syncthreads();
        int cur = 0;
        for (int kt = 0; kt < NTL; ++kt) {
            if (kt + 1 < NTL) {
                #pragma unroll
                for (int i = 0; i < LV4; ++i)
                    pre[i] = wl4[(size_t)(kt + 1) * (KTL * C / 4) + i * 256 + t];
            }
            if (t < C) {
                const float* wb = wbuf[cur];
                #pragma unroll
                for (int k4 = 0; k4 < KTL / 4; ++k4) {
                    float4 xv[ROWS];
                    #pragma unroll
                    for (int r = 0; r < ROWS; ++r)
                        xv[r] = ((const float4*)xs[r])[kt * (KTL / 4) + k4];
                    #pragma unroll
                    for (int j = 0; j < 4; ++j) {
                        float wv = wb[(k4 * 4 + j) * C + t];
                        #pragma unroll
                        for (int r = 0; r < ROWS; ++r)
                            acc[r] = fmaf(((const float*)&xv[r])[j], wv, acc[r]);
                    }
                }
            }
            if (kt + 1 < NTL) {
                #pragma unroll
                for (int i = 0; i < LV4; ++i)
                    ((float4*)wbuf[cur ^ 1])[i * 256 + t] = pre[i];
            }
            __syncthreads();
            cur ^= 1;
        }
        if (t < C) {
            #pragma unroll
            for (int r = 0; r < ROWS; ++r)
                out[(size_t)(row0 + r) * C + t] = acc[r];
        }
    }

    // part_label / part_batch tails (as float, matching float32 d_out)
    if (t < ROWS) {
        const int row = row0 + t;
        out[(size_t)NSEG * C + row] = (float)(row % C);
        out[(size_t)NSEG * C + NSEG + row] = (float)(row / C);
    }
}

extern "C" void kernel_launch(void* const* d_in, const int* in_sizes, int n_in,
                              void* d_out, int out_size, void* d_ws, size_t ws_size,
                              hipStream_t stream) {
    const float* feat  = (const float*)d_in[0];
    const int*   label = (const int*)d_in[1];
    const float* w1    = (const float*)d_in[2];
    const float* b1    = (const float*)d_in[3];
    const float* w2    = (const float*)d_in[4];
    const float* b2    = (const float*)d_in[5];
    const float* wl    = (const float*)d_in[6];
    const float* bl    = (const float*)d_in[7];
    float* out = (float*)d_out;

    int*   counts = (int*)d_ws;
    float* pooled = (float*)((char*)d_ws + ((NSEG * sizeof(int) + 255) / 256) * 256);

    count_kernel<<<B, 256, 0, stream>>>(label, counts);
    pool_kernel<<<B * F_DIM, 256, 0, stream>>>(feat, label, counts, pooled);
    mlp_kernel<<<NBLK, 256, 0, stream>>>(pooled, w1, b1, w2, b2, wl, bl, out);
}

// Round 3
// 74.027 us; speedup vs baseline: 1.4422x; 1.4422x over previous
//
#include <hip/hip_runtime.h>

#define B 16
#define F_DIM 256
#define P 8192
#define C 96
#define H 256
#define NSEG (B * C)          // 1536

// order-preserving float <-> uint mapping for atomicMax-based float max
__device__ __forceinline__ unsigned f2key(float x) {
    unsigned u = __float_as_uint(x);
    return (u & 0x80000000u) ? ~u : (u | 0x80000000u);
}
__device__ __forceinline__ float key2f(unsigned k) {
    unsigned u = (k & 0x80000000u) ? (k & 0x7FFFFFFFu) : ~k;
    return __uint_as_float(u);
}

__global__ __launch_bounds__(256) void count_kernel(const int* __restrict__ label,
                                                    int* __restrict__ counts) {
    __shared__ int hist[C];
    const int b = blockIdx.x;
    const int t = threadIdx.x;
    if (t < C) hist[t] = 0;
    __syncthreads();
    const int* lrow = label + b * P;
    for (int p = t; p < P; p += 256) {
        atomicAdd(&hist[lrow[p]], 1);
    }
    __syncthreads();
    if (t < C) counts[b * C + t] = hist[t];
}

// one block per (b, f): stream 8192 floats + labels, LDS atomicMax per class
__global__ __launch_bounds__(256) void pool_kernel(const float* __restrict__ feat,
                                                   const int* __restrict__ label,
                                                   const int* __restrict__ counts,
                                                   float* __restrict__ pooled) {
    __shared__ unsigned smax[C];
    const int blk = blockIdx.x;
    const int b = blk >> 8;       // / F_DIM
    const int f = blk & 255;      // % F_DIM
    const int t = threadIdx.x;
    if (t < C) smax[t] = 0u;      // key(-inf) > 0, so 0 is a safe identity
    __syncthreads();

    const float4* frow4 = (const float4*)(feat + ((size_t)b * F_DIM + f) * P);
    const int4*   lrow4 = (const int4*)(label + (size_t)b * P);
    for (int i = t; i < P / 4; i += 256) {
        float4 v = frow4[i];
        int4   c = lrow4[i];
        atomicMax(&smax[c.x], f2key(v.x));
        atomicMax(&smax[c.y], f2key(v.y));
        atomicMax(&smax[c.z], f2key(v.z));
        atomicMax(&smax[c.w], f2key(v.w));
    }
    __syncthreads();

    if (t < C) {
        const int cnt = counts[b * C + t];
        const float v = key2f(smax[t]);
        float r = (cnt == 0) ? 0.0f : ((cnt == P) ? v : fmaxf(v, 0.0f));
        pooled[(size_t)(b * C + t) * F_DIM + f] = r;
    }
}

// dense layer: y[NSEG x OUTW] = (relu?)(x[NSEG x H] @ w[H x OUTW] + bias)
// block: 4 rows x COLS cols, split-k by 2 (threads 0-127 low half, 128-255 high).
// grid: (NSEG/4, OUTW/COLS). 2 barriers total, no per-tile sync.
template <int OUTW, int COLS, int RELU>
__global__ __launch_bounds__(256) void dense_kernel(const float* __restrict__ x,
                                                    const float* __restrict__ w,
                                                    const float* __restrict__ bias,
                                                    float* __restrict__ y,
                                                    float* __restrict__ tails) {
    __shared__ float xs[4][H];
    __shared__ float ps[2][4][COLS];
    const int t = threadIdx.x;
    const int row0 = blockIdx.x * 4;
    const int bj0 = blockIdx.y * COLS;

    // stage 4 rows of x (4 x 256 floats), coalesced float4
    {
        const int r = t >> 6, c4 = (t & 63) << 2;
        *(float4*)&xs[r][c4] = *(const float4*)&x[(size_t)(row0 + r) * H + c4];
    }
    __syncthreads();

    const int kh = t >> 7;             // k-half 0/1 (wave-uniform)
    const int u = t & 127;
    constexpr int NQ = COLS / 4;       // col-quads per tile
    const int jq = u % NQ;
    const int r = u / NQ;
    const int j0 = bj0 + jq * 4;

    if (r < 4) {
        const float4* w4 = (const float4*)w;
        const int kbase = kh * (H / 2);
        float4 acc = {0.f, 0.f, 0.f, 0.f};
        #pragma unroll 8
        for (int k = 0; k < H / 2; ++k) {
            const int kk = kbase + k;
            const float4 wv = w4[(kk * OUTW + j0) >> 2];
            const float xv = xs[r][kk];
            acc.x = fmaf(xv, wv.x, acc.x);
            acc.y = fmaf(xv, wv.y, acc.y);
            acc.z = fmaf(xv, wv.z, acc.z);
            acc.w = fmaf(xv, wv.w, acc.w);
        }
        *(float4*)&ps[kh][r][jq * 4] = acc;
    }
    __syncthreads();

    // reduce halves + bias (+relu), write out
    for (int e = t; e < 4 * COLS; e += 256) {
        const int rr = e / COLS, j = e % COLS;
        float v = ps[0][rr][j] + ps[1][rr][j] + bias[bj0 + j];
        if (RELU) v = fmaxf(v, 0.0f);
        y[(size_t)(row0 + rr) * OUTW + bj0 + j] = v;
    }

    // part_label / part_batch tails (only last layer passes tails != null)
    if (tails != nullptr && t < 4) {
        const int row = row0 + t;
        tails[row] = (float)(row % C);
        tails[NSEG + row] = (float)(row / C);
    }
}

extern "C" void kernel_launch(void* const* d_in, const int* in_sizes, int n_in,
                              void* d_out, int out_size, void* d_ws, size_t ws_size,
                              hipStream_t stream) {
    const float* feat  = (const float*)d_in[0];
    const int*   label = (const int*)d_in[1];
    const float* w1    = (const float*)d_in[2];
    const float* b1    = (const float*)d_in[3];
    const float* w2    = (const float*)d_in[4];
    const float* b2    = (const float*)d_in[5];
    const float* wl    = (const float*)d_in[6];
    const float* bl    = (const float*)d_in[7];
    float* out = (float*)d_out;

    char* ws = (char*)d_ws;
    int*   counts = (int*)ws;                              // 6 KB
    float* pooled = (float*)(ws + 8192);                   // 1.5 MB
    float* h1     = (float*)(ws + 8192 + NSEG * H * 4);    // 1.5 MB
    float* h2     = (float*)(ws + 8192 + 2 * NSEG * H * 4);// 1.5 MB

    count_kernel<<<B, 256, 0, stream>>>(label, counts);
    pool_kernel<<<B * F_DIM, 256, 0, stream>>>(feat, label, counts, pooled);
    dense_kernel<H, 128, 1><<<dim3(NSEG / 4, 2), 256, 0, stream>>>(pooled, w1, b1, h1, nullptr);
    dense_kernel<H, 128, 1><<<dim3(NSEG / 4, 2), 256, 0, stream>>>(h1, w2, b2, h2, nullptr);
    dense_kernel<C, 96, 0><<<dim3(NSEG / 4, 1), 256, 0, stream>>>(h2, wl, bl, out, out + (size_t)NSEG * C);
}

// Round 4
// 53.436 us; speedup vs baseline: 1.9980x; 1.3853x over previous
//
#include <hip/hip_runtime.h>

#define B 16
#define F_DIM 256
#define P 8192
#define C 96
#define H 256
#define NSEG (B * C)          // 1536

// order-preserving float <-> uint mapping for atomicMax-based float max
__device__ __forceinline__ unsigned f2key(float x) {
    unsigned u = __float_as_uint(x);
    return (u & 0x80000000u) ? ~u : (u | 0x80000000u);
}
__device__ __forceinline__ float key2f(unsigned k) {
    unsigned u = (k & 0x80000000u) ? (k & 0x7FFFFFFFu) : ~k;
    return __uint_as_float(u);
}

__global__ __launch_bounds__(256) void count_kernel(const int* __restrict__ label,
                                                    int* __restrict__ counts) {
    __shared__ int hist[C];
    const int b = blockIdx.x;
    const int t = threadIdx.x;
    if (t < C) hist[t] = 0;
    __syncthreads();
    const int* lrow = label + b * P;
    for (int p = t; p < P; p += 256) {
        atomicAdd(&hist[lrow[p]], 1);
    }
    __syncthreads();
    if (t < C) counts[b * C + t] = hist[t];
}

// one block per (b, f): stream 8192 floats + labels, LDS atomicMax per class
__global__ __launch_bounds__(256) void pool_kernel(const float* __restrict__ feat,
                                                   const int* __restrict__ label,
                                                   const int* __restrict__ counts,
                                                   float* __restrict__ pooled) {
    __shared__ unsigned smax[C];
    const int blk = blockIdx.x;
    const int b = blk >> 8;       // / F_DIM
    const int f = blk & 255;      // % F_DIM
    const int t = threadIdx.x;
    if (t < C) smax[t] = 0u;      // key(-inf) > 0, so 0 is a safe identity
    __syncthreads();

    const float4* frow4 = (const float4*)(feat + ((size_t)b * F_DIM + f) * P);
    const int4*   lrow4 = (const int4*)(label + (size_t)b * P);
    for (int i = t; i < P / 4; i += 256) {
        float4 v = frow4[i];
        int4   c = lrow4[i];
        atomicMax(&smax[c.x], f2key(v.x));
        atomicMax(&smax[c.y], f2key(v.y));
        atomicMax(&smax[c.z], f2key(v.z));
        atomicMax(&smax[c.w], f2key(v.w));
    }
    __syncthreads();

    if (t < C) {
        const int cnt = counts[b * C + t];
        const float v = key2f(smax[t]);
        float r = (cnt == 0) ? 0.0f : ((cnt == P) ? v : fmaxf(v, 0.0f));
        pooled[(size_t)(b * C + t) * F_DIM + f] = r;
    }
}

// dense layer: y[NSEG x OUTW] = (relu?)(x[NSEG x H] @ w[H x OUTW] + bias)
// block: 8 rows x COLS cols; 256 threads = 16 col-quads x 16 k-slices (split-K).
// Each thread: 16 independent float4 weight loads (fully unrolled), 8-row reuse,
// then LDS reduce over the 16 slices. Grid: (NSEG/8, OUTW/COLS).
template <int COLS, int RELU, int OUTW>
__global__ __launch_bounds__(256, 3) void dense_kernel(const float* __restrict__ x,
                                                       const float* __restrict__ w,
                                                       const float* __restrict__ bias,
                                                       float* __restrict__ y,
                                                       float* __restrict__ tails) {
    constexpr int NQ = COLS / 4;       // active col-quads (<= 16)
    __shared__ float xs[8][H];
    __shared__ float ps[8][COLS][17];  // [row][col][slice], padded
    const int t = threadIdx.x;
    const int row0 = blockIdx.x * 8;
    const int bj0 = blockIdx.y * COLS;

    // stage 8 rows of x (8 x 256 floats = 512 float4), coalesced
    {
        int i0 = t, i1 = t + 256;
        ((float4*)xs)[i0] = ((const float4*)(x + (size_t)row0 * H))[i0];
        ((float4*)xs)[i1] = ((const float4*)(x + (size_t)row0 * H))[i1];
    }
    __syncthreads();

    const int s = t >> 4;     // k-slice 0..15
    const int jq = t & 15;    // col-quad

    if (jq < NQ) {
        const float4* w4 = (const float4*)w;
        constexpr int WS4 = OUTW / 4;   // float4 per weight row
        const int wq = (bj0 >> 2) + jq;
        const int kbase = s * 16;
        float4 acc[8];
        #pragma unroll
        for (int r = 0; r < 8; ++r) acc[r] = (float4){0.f, 0.f, 0.f, 0.f};

        #pragma unroll
        for (int i = 0; i < 16; ++i) {
            const int k = kbase + i;
            const float4 wv = w4[k * WS4 + wq];
            #pragma unroll
            for (int r = 0; r < 8; ++r) {
                const float xv = xs[r][k];
                acc[r].x = fmaf(xv, wv.x, acc[r].x);
                acc[r].y = fmaf(xv, wv.y, acc[r].y);
                acc[r].z = fmaf(xv, wv.z, acc[r].z);
                acc[r].w = fmaf(xv, wv.w, acc[r].w);
            }
        }
        #pragma unroll
        for (int r = 0; r < 8; ++r) {
            ps[r][jq * 4 + 0][s] = acc[r].x;
            ps[r][jq * 4 + 1][s] = acc[r].y;
            ps[r][jq * 4 + 2][s] = acc[r].z;
            ps[r][jq * 4 + 3][s] = acc[r].w;
        }
    }
    __syncthreads();

    // reduce 16 slices + bias (+relu), write out
    for (int e = t; e < 8 * COLS; e += 256) {
        const int r = e / COLS, j = e % COLS;
        float v = bias[bj0 + j];
        #pragma unroll
        for (int q = 0; q < 16; ++q) v += ps[r][j][q];
        if (RELU) v = fmaxf(v, 0.0f);
        y[(size_t)(row0 + r) * OUTW + bj0 + j] = v;
    }

    // part_label / part_batch tails (only last layer passes tails != null)
    if (tails != nullptr && t < 8) {
        const int row = row0 + t;
        tails[row] = (float)(row % C);
        tails[NSEG + row] = (float)(row / C);
    }
}

extern "C" void kernel_launch(void* const* d_in, const int* in_sizes, int n_in,
                              void* d_out, int out_size, void* d_ws, size_t ws_size,
                              hipStream_t stream) {
    const float* feat  = (const float*)d_in[0];
    const int*   label = (const int*)d_in[1];
    const float* w1    = (const float*)d_in[2];
    const float* b1    = (const float*)d_in[3];
    const float* w2    = (const float*)d_in[4];
    const float* b2    = (const float*)d_in[5];
    const float* wl    = (const float*)d_in[6];
    const float* bl    = (const float*)d_in[7];
    float* out = (float*)d_out;

    char* ws = (char*)d_ws;
    int*   counts = (int*)ws;                              // 6 KB
    float* pooled = (float*)(ws + 8192);                   // 1.5 MB
    float* h1     = (float*)(ws + 8192 + NSEG * H * 4);    // 1.5 MB
    float* h2     = (float*)(ws + 8192 + 2 * NSEG * H * 4);// 1.5 MB

    count_kernel<<<B, 256, 0, stream>>>(label, counts);
    pool_kernel<<<B * F_DIM, 256, 0, stream>>>(feat, label, counts, pooled);
    dense_kernel<64, 1, H><<<dim3(NSEG / 8, 4), 256, 0, stream>>>(pooled, w1, b1, h1, nullptr);
    dense_kernel<64, 1, H><<<dim3(NSEG / 8, 4), 256, 0, stream>>>(h1, w2, b2, h2, nullptr);
    dense_kernel<48, 0, C><<<dim3(NSEG / 8, 2), 256, 0, stream>>>(h2, wl, bl, out, out + (size_t)NSEG * C);
}